// Round 3
// baseline (2929.544 us; speedup 1.0000x reference)
//
#include <hip/hip_runtime.h>
#include <math.h>
#include <stdio.h>

#define NROWS 8192
#define KDIM 2048
#define VOCAB 50257
#define VOCAB_PAD 50432        // 197 * 256
#define NTILES 197
#define NCHUNKS 8
#define BM 256
#define BN 256
#define BK 64
#define KSTEPS (KDIM / BK)     // 32
#define ROWBLKS (NROWS / BM)   // 32
#define L2E 1.44269504088896340736f
#define SMEM_BYTES 147456

typedef __bf16 bf16x8 __attribute__((ext_vector_type(8)));
typedef float f32x4 __attribute__((ext_vector_type(4)));

__device__ __forceinline__ unsigned short f2b(float f) {
  unsigned int u = __float_as_uint(f);
  u += 0x7fffu + ((u >> 16) & 1u);   // round-to-nearest-even
  return (unsigned short)(u >> 16);
}

// async global->LDS, 16B per lane, wave-uniform LDS base + lane*16
#define GLL16(g, l)                                                         \
  __builtin_amdgcn_global_load_lds(                                         \
      (const __attribute__((address_space(1))) void*)(g),                   \
      (__attribute__((address_space(3))) void*)(l), 16, 0, 0)

// ---------------- convert kernels (f32 -> bf16) ----------------
__global__ void convert_x_kernel(const float4* __restrict__ src,
                                 ushort4* __restrict__ dst) {
  const long long total = (long long)NROWS * KDIM / 4;
  for (long long i = (long long)blockIdx.x * blockDim.x + threadIdx.x;
       i < total; i += (long long)gridDim.x * blockDim.x) {
    float4 v = src[i];
    ushort4 o;
    o.x = f2b(v.x); o.y = f2b(v.y); o.z = f2b(v.z); o.w = f2b(v.w);
    dst[i] = o;
  }
}

__global__ void convert_w_kernel(const float4* __restrict__ src,
                                 ushort4* __restrict__ dst) {
  const long long total  = (long long)VOCAB_PAD * KDIM / 4;
  const long long stotal = (long long)VOCAB * KDIM / 4;
  for (long long i = (long long)blockIdx.x * blockDim.x + threadIdx.x;
       i < total; i += (long long)gridDim.x * blockDim.x) {
    float4 v;
    if (i < stotal) v = src[i];
    else { v.x = v.y = v.z = v.w = 0.f; }  // zero pad rows
    ushort4 o;
    o.x = f2b(v.x); o.y = f2b(v.y); o.z = f2b(v.z); o.w = f2b(v.w);
    dst[i] = o;
  }
}

// ---------------- fused 256^2 8-phase GEMM + online softmax ----------------
// 512 threads = 8 waves (2M x 4N). LDS: A/B double-buffered 256x64 bf16,
// XOR-swizzled (T2, rule #21: linear LDS dest + inverse-swizzled global src +
// swizzled ds_read). Counted vmcnt(8) keeps one K-tile of prefetch in flight
// across raw barriers (T3+T4); setprio around MFMA clusters (T5).

#define LGKM0  asm volatile("s_waitcnt lgkmcnt(0)" ::: "memory")
#define VM8    asm volatile("s_waitcnt vmcnt(8)" ::: "memory")
#define VM0    asm volatile("s_waitcnt vmcnt(0)" ::: "memory")
#define BAR    __builtin_amdgcn_s_barrier()
#define SCHED0 __builtin_amdgcn_sched_barrier(0)

#define STAGE(BUF, KT, WBASE)                                               \
  do {                                                                      \
    const int kb_ = (KT) * BK;                                              \
    _Pragma("unroll")                                                       \
    for (int ii = 0; ii < 4; ++ii) {                                        \
      GLL16(xb + aoff[ii] + kb_,                                            \
            smem + ((((BUF) * 2048) + (ii * 8 + w) * 64) << 4));            \
      GLL16((WBASE) + boff[ii] + kb_,                                       \
            smem + 65536 + ((((BUF) * 2048) + (ii * 8 + w) * 64) << 4));    \
    }                                                                       \
  } while (0)

#define LOAD_AF(BUF, QM)                                                    \
  _Pragma("unroll") for (int mfi = 0; mfi < 4; ++mfi)                       \
  _Pragma("unroll") for (int ks = 0; ks < 2; ++ks)                          \
    af[mfi][ks] = *(const bf16x8*)&smA[(((BUF) * 256 + wm * 128 +           \
        (QM) * 64 + mfi * 16 + c0) << 6) + koff[ks]];

#define LOAD_BF(BUF, QN)                                                    \
  _Pragma("unroll") for (int nfj = 0; nfj < 2; ++nfj)                       \
  _Pragma("unroll") for (int ks = 0; ks < 2; ++ks)                          \
    bfv[nfj][ks] = *(const bf16x8*)&smB[(((BUF) * 256 + wn * 64 +           \
        (QN) * 32 + nfj * 16 + c0) << 6) + koff[ks]];

#define COMP(QM, QN)                                                        \
  __builtin_amdgcn_s_setprio(1);                                            \
  _Pragma("unroll") for (int mfi = 0; mfi < 4; ++mfi)                       \
  _Pragma("unroll") for (int nfj = 0; nfj < 2; ++nfj)                       \
  _Pragma("unroll") for (int ks = 0; ks < 2; ++ks)                          \
    acc[(QM) * 4 + mfi][(QN) * 2 + nfj] =                                   \
        __builtin_amdgcn_mfma_f32_16x16x32_bf16(                            \
            af[mfi][ks], bfv[nfj][ks],                                      \
            acc[(QM) * 4 + mfi][(QN) * 2 + nfj], 0, 0, 0);                  \
  __builtin_amdgcn_s_setprio(0);

// 4 phases per K-tile; quadrant order (0,0),(0,1),(1,1),(1,0) reuses operands.
// Phase D: all reads of this buffer are complete (LGKM0 before BAR) -> buffer
// is dead -> safe to STAGE K-tile T+2 into it. vmcnt(8) leaves those 8 loads
// in flight while waiting the other buffer's 8 (issued one K-tile ago).
#define KTILE(BUF, T, LASTPAIR, WBASE)                                      \
  do {                                                                      \
    LOAD_AF(BUF, 0); LOAD_BF(BUF, 0);                                       \
    BAR; LGKM0; COMP(0, 0); BAR;                                            \
    LOAD_BF(BUF, 1);                                                        \
    BAR; LGKM0; COMP(0, 1); BAR;                                            \
    LOAD_AF(BUF, 1);                                                        \
    BAR; LGKM0; COMP(1, 1); BAR;                                            \
    LOAD_BF(BUF, 0);                                                        \
    LGKM0; BAR; SCHED0;                                                     \
    if (!(LASTPAIR)) { STAGE(BUF, (T) + 2, WBASE); }                        \
    SCHED0;                                                                 \
    COMP(1, 0);                                                             \
    SCHED0;                                                                 \
    if (!(LASTPAIR)) { VM8; } else { VM0; }                                 \
    BAR;                                                                    \
  } while (0)

__global__ void __launch_bounds__(512, 2)
gemm_ce_kernel(const unsigned short* __restrict__ xb,
               const unsigned short* __restrict__ wb,
               const float* __restrict__ bias,
               const int* __restrict__ targ,
               float* __restrict__ pm, float* __restrict__ ps,
               float* __restrict__ tlogit) {
  extern __shared__ char smem[];
  unsigned short* smA = (unsigned short*)smem;            // [2][256][64]
  unsigned short* smB = (unsigned short*)(smem + 65536);  // [2][256][64]
  float* m_w   = (float*)(smem + 131072);  // [4][256]
  float* s_w   = (float*)(smem + 135168);  // [4][256]
  float* t_w   = (float*)(smem + 139264);  // [4][256]
  float* M_run = (float*)(smem + 143360);  // [256]
  float* S_run = (float*)(smem + 144384);  // [256]
  float* T_run = (float*)(smem + 145408);  // [256]
  int*   targ_s = (int*)(smem + 146432);   // [256]

  const int tid  = threadIdx.x;
  const int lane = tid & 63;
  const int w    = tid >> 6;      // wave 0..7
  const int wm   = w >> 2;        // 0..1 -> rows wm*128..
  const int wn   = w & 3;         // 0..3 -> cols wn*64..
  const int g    = lane >> 4;
  const int c0   = lane & 15;
  const int swz  = c0 & 7;

  const int bid    = blockIdx.x;
  const int chunk  = bid & 7;     // XCD-aligned: same chunk -> same XCD L2
  const int rowblk = bid >> 3;    // 0..31
  const int row0   = rowblk * BM;
  const int tile_start = (chunk * NTILES) / NCHUNKS;
  const int tile_end   = ((chunk + 1) * NTILES) / NCHUNKS;

  // per-thread staging offsets (inverse-swizzled source, rule #21)
  int aoff[4], boff[4];
#pragma unroll
  for (int ii = 0; ii < 4; ++ii) {
    const int cidx = (ii * 8 + w) * 64 + lane;   // 16B-chunk index 0..2047
    const int r    = cidx >> 3;                  // tile row 0..255
    const int k8   = (cidx & 7) ^ (r & 7);
    aoff[ii] = (row0 + r) * KDIM + k8 * 8;
    boff[ii] = r * KDIM + k8 * 8;
  }
  int koff[2];
#pragma unroll
  for (int ks = 0; ks < 2; ++ks) koff[ks] = ((ks * 4 + g) ^ swz) * 8;

  if (tid < BM) {
    int t = targ[row0 + tid];
    targ_s[tid] = (t < 0) ? 0 : t;
    M_run[tid] = -1e30f;
    S_run[tid] = 0.f;
    T_run[tid] = -1e30f;
  }
  __syncthreads();

  // pipeline prologue: stage first two K-tiles of the first vocab tile
  {
    const unsigned short* wB0 = wb + (size_t)(tile_start * BN) * KDIM;
    STAGE(0, 0, wB0);
    STAGE(1, 1, wB0);
    SCHED0;
  }

#pragma unroll 1
  for (int tile = tile_start; tile < tile_end; ++tile) {
    const unsigned short* wB = wb + (size_t)(tile * BN) * KDIM;
    const int vcol0 = tile * BN;

    VM8;   // buf0 of this tile landed (buf1's 8 may stay in flight)
    BAR;

    // bias preload BEFORE any further VMEM so later vmcnt(8) stays valid
    float bv[4];
#pragma unroll
    for (int nf = 0; nf < 4; ++nf) {
      const int col = vcol0 + wn * 64 + nf * 16 + c0;
      bv[nf] = (col < VOCAB) ? bias[col] : 0.f;
    }

    f32x4 acc[8][4];
#pragma unroll
    for (int mf = 0; mf < 8; ++mf)
#pragma unroll
      for (int nf = 0; nf < 4; ++nf) acc[mf][nf] = (f32x4){0.f, 0.f, 0.f, 0.f};

    bf16x8 af[4][2], bfv[2][2];

#pragma unroll 1
    for (int tt = 0; tt < KSTEPS / 2; ++tt) {
      const bool lastpair = (tt == KSTEPS / 2 - 1);
      KTILE(0, 2 * tt,     lastpair, wB);
      KTILE(1, 2 * tt + 1, lastpair, wB);
    }

    // buffers are dead; overlap next tile's first two K-tile stages with epilogue
    SCHED0;
    if (tile + 1 < tile_end) {
      const unsigned short* wBn = wb + (size_t)((tile + 1) * BN) * KDIM;
      STAGE(0, 0, wBn);
      STAGE(1, 1, wBn);
    }
    SCHED0;

    // ---- epilogue: per-wave softmax partials (no VMEM -> vmcnt untouched)
#pragma unroll
    for (int mf = 0; mf < 8; ++mf) {
#pragma unroll
      for (int reg = 0; reg < 4; ++reg) {
        const int rl  = wm * 128 + mf * 16 + g * 4 + reg;
        const int tgt = targ_s[rl];
        float vals[4];
        float vmax = -1e30f, tv = -1e30f;
#pragma unroll
        for (int nf = 0; nf < 4; ++nf) {
          const int col = vcol0 + wn * 64 + nf * 16 + c0;
          float v = acc[mf][nf][reg] + bv[nf];
          v = (col < VOCAB) ? v : -1e30f;
          vals[nf] = v;
          vmax = fmaxf(vmax, v);
          if (col == tgt) tv = v;
        }
        vmax = fmaxf(vmax, __shfl_xor(vmax, 1));
        vmax = fmaxf(vmax, __shfl_xor(vmax, 2));
        vmax = fmaxf(vmax, __shfl_xor(vmax, 4));
        vmax = fmaxf(vmax, __shfl_xor(vmax, 8));
        float ss = 0.f;
#pragma unroll
        for (int nf = 0; nf < 4; ++nf) ss += exp2f((vals[nf] - vmax) * L2E);
        ss += __shfl_xor(ss, 1);
        ss += __shfl_xor(ss, 2);
        ss += __shfl_xor(ss, 4);
        ss += __shfl_xor(ss, 8);
        tv = fmaxf(tv, __shfl_xor(tv, 1));
        tv = fmaxf(tv, __shfl_xor(tv, 2));
        tv = fmaxf(tv, __shfl_xor(tv, 4));
        tv = fmaxf(tv, __shfl_xor(tv, 8));
        if (c0 == 0) {
          m_w[wn * 256 + rl] = vmax;
          s_w[wn * 256 + rl] = ss;
          t_w[wn * 256 + rl] = tv;
        }
      }
    }
    LGKM0;   // lgkm-only wait: the 16 prefetch loads stay in flight
    BAR;
    if (tid < BM) {
      float mt = m_w[tid], st = s_w[tid], tvt = t_w[tid];
#pragma unroll
      for (int j = 1; j < 4; ++j) {
        const float mj = m_w[j * 256 + tid], sj = s_w[j * 256 + tid];
        const float nm = fmaxf(mt, mj);
        st = st * exp2f((mt - nm) * L2E) + sj * exp2f((mj - nm) * L2E);
        mt = nm;
        tvt = fmaxf(tvt, t_w[j * 256 + tid]);
      }
      const float M = M_run[tid], S = S_run[tid];
      const float nm = fmaxf(M, mt);
      S_run[tid] = S * exp2f((M - nm) * L2E) + st * exp2f((mt - nm) * L2E);
      M_run[tid] = nm;
      T_run[tid] = fmaxf(T_run[tid], tvt);
    }
    LGKM0;
    BAR;
  }

  if (tid < BM) {
    pm[(size_t)chunk * NROWS + row0 + tid] = M_run[tid];
    ps[(size_t)chunk * NROWS + row0 + tid] = S_run[tid];
    const float tv = T_run[tid];
    if (tv > -1e29f) tlogit[row0 + tid] = tv;  // exactly one chunk hits per row
  }
}

// ---------------- merge partials -> per-row NLL ----------------
__global__ void merge_rows_kernel(const float* __restrict__ pm,
                                  const float* __restrict__ ps,
                                  const float* __restrict__ tlogit,
                                  const int* __restrict__ targ,
                                  float* __restrict__ nll) {
  const int r = blockIdx.x * blockDim.x + threadIdx.x;
  if (r >= NROWS) return;
  float M = -1e30f;
#pragma unroll
  for (int j = 0; j < NCHUNKS; ++j) M = fmaxf(M, pm[j * NROWS + r]);
  float S = 0.f;
#pragma unroll
  for (int j = 0; j < NCHUNKS; ++j)
    S += ps[j * NROWS + r] * exp2f((pm[j * NROWS + r] - M) * L2E);
  const int t = targ[r];
  nll[r] = (t == -100) ? 0.f : (M + logf(S) - tlogit[r]);
}

// ---------------- final mean ----------------
__global__ void final_reduce_kernel(const float* __restrict__ nll,
                                    const int* __restrict__ targ,
                                    float* __restrict__ out) {
  __shared__ float ssum[256];
  __shared__ float scnt[256];
  const int tid = threadIdx.x;
  float s = 0.f, c = 0.f;
  for (int r = tid; r < NROWS; r += 256) {
    s += nll[r];
    c += (targ[r] != -100) ? 1.f : 0.f;
  }
  ssum[tid] = s; scnt[tid] = c;
  __syncthreads();
  for (int off = 128; off > 0; off >>= 1) {
    if (tid < off) { ssum[tid] += ssum[tid + off]; scnt[tid] += scnt[tid + off]; }
    __syncthreads();
  }
  if (tid == 0) out[0] = ssum[0] / fmaxf(scnt[0], 1.f);
}

extern "C" void kernel_launch(void* const* d_in, const int* in_sizes, int n_in,
                              void* d_out, int out_size, void* d_ws, size_t ws_size,
                              hipStream_t stream) {
  const float* x    = (const float*)d_in[0];
  const float* W    = (const float*)d_in[1];
  const float* bias = (const float*)d_in[2];
  const int*   targ = (const int*)d_in[3];
  float* out = (float*)d_out;

  char* ws = (char*)d_ws;
  const size_t wb_bytes = (size_t)VOCAB_PAD * KDIM * 2;  // 206,569,472
  const size_t xb_bytes = (size_t)NROWS * KDIM * 2;      //  33,554,432
  const size_t pm_bytes = (size_t)NCHUNKS * NROWS * 4;   //     262,144
  const size_t tl_bytes = (size_t)NROWS * 4;

  size_t off = 0;
  unsigned short* wb = (unsigned short*)(ws + off); off += wb_bytes;
  unsigned short* xb = (unsigned short*)(ws + off); off += xb_bytes;
  float* pm   = (float*)(ws + off); off += pm_bytes;
  float* psum = (float*)(ws + off); off += pm_bytes;
  float* tlog = (float*)(ws + off); off += tl_bytes;
  float* nll  = (float*)(ws + off); off += tl_bytes;

  if (ws_size < off) {
    fprintf(stderr, "kernel_launch: ws too small (%zu < %zu)\n", ws_size, off);
    return;
  }

  (void)hipFuncSetAttribute((const void*)gemm_ce_kernel,
                            hipFuncAttributeMaxDynamicSharedMemorySize,
                            SMEM_BYTES);

  convert_w_kernel<<<4096, 256, 0, stream>>>((const float4*)W, (ushort4*)wb);
  convert_x_kernel<<<2048, 256, 0, stream>>>((const float4*)x, (ushort4*)xb);
  gemm_ce_kernel<<<ROWBLKS * NCHUNKS, 512, SMEM_BYTES, stream>>>(
      xb, wb, bias, targ, pm, psum, tlog);
  merge_rows_kernel<<<(NROWS + 255) / 256, 256, 0, stream>>>(pm, psum, tlog,
                                                             targ, nll);
  final_reduce_kernel<<<1, 256, 0, stream>>>(nll, targ, out);
}

// Round 4
// 2563.114 us; speedup vs baseline: 1.1430x; 1.1430x over previous
//
#include <hip/hip_runtime.h>
#include <math.h>
#include <stdio.h>

#define NROWS 8192
#define KDIM 2048
#define VOCAB 50257
#define VOCAB_PAD 50432        // 197 * 256
#define NTILES 197
#define NCHUNKS 8
#define BM 256
#define BN 256
#define BK 64
#define ROWBLKS (NROWS / BM)   // 32
#define MAXTILES 25
#define L2E 1.44269504088896340736f

// LDS map (bytes)
#define OFF_A    0        // [2][256][64] bf16 = 65536
#define OFF_B    65536    // [2][256][64] bf16 = 65536
#define OFF_BIAS 131072   // [25][256] bf16    = 12800
#define OFF_MW   143872   // [4][256] f32      = 4096
#define OFF_SW   147968
#define OFF_TW   152064
#define OFF_MR   156160   // [256] f32
#define OFF_SR   157184
#define OFF_TR   158208
#define OFF_TS   159232   // [256] int
#define SMEM_BYTES 160256

typedef __bf16 bf16x8 __attribute__((ext_vector_type(8)));
typedef float f32x4 __attribute__((ext_vector_type(4)));

__device__ __forceinline__ unsigned short f2b(float f) {
  unsigned int u = __float_as_uint(f);
  u += 0x7fffu + ((u >> 16) & 1u);   // round-to-nearest-even
  return (unsigned short)(u >> 16);
}

// async global->LDS, 16B per lane, wave-uniform LDS base + lane*16
#define GLL16(g, l)                                                         \
  __builtin_amdgcn_global_load_lds(                                         \
      (const __attribute__((address_space(1))) void*)(g),                   \
      (__attribute__((address_space(3))) void*)(l), 16, 0, 0)

// ---------------- convert kernels (f32 -> bf16) ----------------
__global__ void convert_x_kernel(const float4* __restrict__ src,
                                 ushort4* __restrict__ dst) {
  const long long total = (long long)NROWS * KDIM / 4;
  for (long long i = (long long)blockIdx.x * blockDim.x + threadIdx.x;
       i < total; i += (long long)gridDim.x * blockDim.x) {
    float4 v = src[i];
    ushort4 o;
    o.x = f2b(v.x); o.y = f2b(v.y); o.z = f2b(v.z); o.w = f2b(v.w);
    dst[i] = o;
  }
}

__global__ void convert_w_kernel(const float4* __restrict__ src,
                                 ushort4* __restrict__ dst) {
  const long long total  = (long long)VOCAB_PAD * KDIM / 4;
  const long long stotal = (long long)VOCAB * KDIM / 4;
  for (long long i = (long long)blockIdx.x * blockDim.x + threadIdx.x;
       i < total; i += (long long)gridDim.x * blockDim.x) {
    float4 v;
    if (i < stotal) v = src[i];
    else { v.x = v.y = v.z = v.w = 0.f; }
    ushort4 o;
    o.x = f2b(v.x); o.y = f2b(v.y); o.z = f2b(v.z); o.w = f2b(v.w);
    dst[i] = o;
  }
}

// ---------------- fused 256^2 8-phase GEMM + online softmax ----------------
// 512 threads = 8 waves (wm 0-1 x wn 0-3). LDS: A/B double-buffered 256x64
// bf16, XOR-swizzled (T2, rule #21). Per K-step: 4 quadrant phases, staging
// spread 4/0/2/2 across phases (T3), single counted vmcnt(4) per K-step (T4),
// setprio around MFMA clusters (T5). No VMEM outside the pipeline (bias is
// pre-staged into LDS) so vmcnt counts stay exact.

#define LGKM0  asm volatile("s_waitcnt lgkmcnt(0)" ::: "memory")
#define VMW4   asm volatile("s_waitcnt vmcnt(4)" ::: "memory")
#define VMW0   asm volatile("s_waitcnt vmcnt(0)" ::: "memory")
#define BAR    __builtin_amdgcn_s_barrier()
#define SCHED0 __builtin_amdgcn_sched_barrier(0)

// stage one 8-row unit of A (rows rbA[II]..+7) for K-step Q
#define STG_A_(II, Q)                                                       \
  do { const int q_ = (Q);                                                  \
    GLL16(xb + aofs##II + ((q_ & 31) << 6),                                 \
          smem + ((q_ & 1) << 15) + adst##II); } while (0)

#define STG_BX_(J, Q)                                                       \
  do { const int q_ = (Q);                                                  \
    GLL16(wb + (size_t)(tile_start + (q_ >> 5)) * (BN * KDIM)               \
             + bofsX##J + ((q_ & 31) << 6),                                 \
          smem + OFF_B + ((q_ & 1) << 15) + bdstX##J); } while (0)

#define STG_BY_(J, Q)                                                       \
  do { const int q_ = (Q);                                                  \
    GLL16(wb + (size_t)(tile_start + (q_ >> 5)) * (BN * KDIM)               \
             + bofsY##J + ((q_ & 31) << 6),                                 \
          smem + OFF_B + ((q_ & 1) << 15) + bdstY##J); } while (0)

#define LDA(B, QM)                                                          \
  _Pragma("unroll") for (int mf = 0; mf < 4; ++mf)                          \
  _Pragma("unroll") for (int ks = 0; ks < 2; ++ks)                          \
    af[mf][ks] = *(const bf16x8*)(smem +                                    \
        ((((B) * 256 + wm * 128 + (QM) * 64 + mf * 16 + c0) << 7) + koff[ks]));

#define LDB(B, QN)                                                          \
  _Pragma("unroll") for (int nf = 0; nf < 2; ++nf)                          \
  _Pragma("unroll") for (int ks = 0; ks < 2; ++ks)                          \
    bf[nf][ks] = *(const bf16x8*)(smem + OFF_B +                            \
        ((((B) * 256 + wn * 64 + (QN) * 32 + nf * 16 + c0) << 7) + koff[ks]));

#define COMP(QM, QN)                                                        \
  __builtin_amdgcn_s_setprio(1);                                            \
  _Pragma("unroll") for (int mf = 0; mf < 4; ++mf)                          \
  _Pragma("unroll") for (int nf = 0; nf < 2; ++nf)                          \
  _Pragma("unroll") for (int ks = 0; ks < 2; ++ks)                          \
    acc[(QM) * 4 + mf][(QN) * 2 + nf] =                                     \
        __builtin_amdgcn_mfma_f32_16x16x32_bf16(                            \
            af[mf][ks], bf[nf][ks],                                         \
            acc[(QM) * 4 + mf][(QN) * 2 + nf], 0, 0, 0);                    \
  __builtin_amdgcn_s_setprio(0);

__global__ void __launch_bounds__(512, 2)
gemm_ce_kernel(const unsigned short* __restrict__ xb,
               const unsigned short* __restrict__ wb,
               const float* __restrict__ bias,
               const int* __restrict__ targ,
               float* __restrict__ pm, float* __restrict__ ps,
               float* __restrict__ tlogit) {
  extern __shared__ char smem[];
  unsigned short* bias_lds = (unsigned short*)(smem + OFF_BIAS);
  float* m_w   = (float*)(smem + OFF_MW);
  float* s_w   = (float*)(smem + OFF_SW);
  float* t_w   = (float*)(smem + OFF_TW);
  float* M_run = (float*)(smem + OFF_MR);
  float* S_run = (float*)(smem + OFF_SR);
  float* T_run = (float*)(smem + OFF_TR);
  int*   targ_s = (int*)(smem + OFF_TS);

  const int tid  = threadIdx.x;
  const int lane = tid & 63;
  const int w    = tid >> 6;      // wave 0..7
  const int wm   = w >> 2;        // row-half
  const int wn   = w & 3;         // col-quarter
  const int g    = lane >> 4;
  const int c0   = lane & 15;
  const int swz  = c0 & 7;

  const int bid    = blockIdx.x;
  const int chunk  = bid & 7;     // XCD-pinned: same chunk -> same XCD L2
  const int rowblk = bid >> 3;
  const int row0   = rowblk * BM;
  const int tile_start = (chunk * NTILES) / NCHUNKS;
  const int tile_end   = ((chunk + 1) * NTILES) / NCHUNKS;
  const int ntb = tile_end - tile_start;
  const int P   = ntb * 32;       // K-step stream length

  // staging geometry: one GLL16 = 8 rows x 8 chunks; src swizzle key
  const int lr = lane >> 3;                 // row within 8-row unit
  const int k8 = (lane & 7) ^ lr;           // inverse-swizzled source chunk
  // A units: ii 0..3 -> row base (ii*8+w)*8 ; ii 0,2 = X-half, ii 1,3 = Y-half
  const int rA0 = (0 * 8 + w) * 8, rA1 = (1 * 8 + w) * 8;
  const int rA2 = (2 * 8 + w) * 8, rA3 = (3 * 8 + w) * 8;
  const int aofs0 = (row0 + rA0 + lr) * KDIM + k8 * 8;
  const int aofs1 = (row0 + rA1 + lr) * KDIM + k8 * 8;
  const int aofs2 = (row0 + rA2 + lr) * KDIM + k8 * 8;
  const int aofs3 = (row0 + rA3 + lr) * KDIM + k8 * 8;
  const int adst0 = rA0 * 128, adst1 = rA1 * 128;
  const int adst2 = rA2 * 128, adst3 = rA3 * 128;
  // B units: X = rows with (r&63)<32 read by QN=0; Y = the rest (QN=1).
  // Each wave stages 2 X-units and 2 Y-units (uniform vmcnt counting).
  const int sX0 = 2 * w, sX1 = 2 * w + 1;
  const int rBX0 = (sX0 >> 2) * 64 + (sX0 & 3) * 8;
  const int rBX1 = (sX1 >> 2) * 64 + (sX1 & 3) * 8;
  const int rBY0 = 32 + rBX0, rBY1 = 32 + rBX1;
  const int bofsX0 = (rBX0 + lr) * KDIM + k8 * 8;
  const int bofsX1 = (rBX1 + lr) * KDIM + k8 * 8;
  const int bofsY0 = (rBY0 + lr) * KDIM + k8 * 8;
  const int bofsY1 = (rBY1 + lr) * KDIM + k8 * 8;
  const int bdstX0 = rBX0 * 128, bdstX1 = rBX1 * 128;
  const int bdstY0 = rBY0 * 128, bdstY1 = rBY1 * 128;

  int koff[2];
#pragma unroll
  for (int ks = 0; ks < 2; ++ks) koff[ks] = (((ks * 4 + g) ^ swz)) << 4;

  // ---- prologue: targets, running state, bias table (keeps VMEM out of loop)
  if (tid < BM) {
    int t = targ[row0 + tid];
    targ_s[tid] = (t < 0) ? 0 : t;
    M_run[tid] = -1e30f;
    S_run[tid] = 0.f;
    T_run[tid] = -1e30f;
  }
  for (int idx = tid; idx < ntb * 256; idx += 512) {
    const int col = tile_start * 256 + idx;
    bias_lds[idx] = (col < VOCAB) ? f2b(bias[col]) : (unsigned short)0;
  }
  LGKM0;
  BAR;

  // ---- pipeline prologue: q=0 fully, q=1's C/D-role parts
  STG_A_(0, 0); STG_A_(1, 0); STG_A_(2, 0); STG_A_(3, 0);
  STG_BX_(0, 0); STG_BX_(1, 0); STG_BY_(0, 0); STG_BY_(1, 0);
  STG_BX_(0, 1); STG_BX_(1, 1); STG_A_(1, 1); STG_A_(3, 1);
  VMW4;   // q=0's 8 loads landed; q=1's 4 may stay in flight
  BAR;

  f32x4 acc[8][4];
#pragma unroll
  for (int mf = 0; mf < 8; ++mf)
#pragma unroll
    for (int nf = 0; nf < 4; ++nf) acc[mf][nf] = (f32x4){0.f, 0.f, 0.f, 0.f};

  bf16x8 af[4][2], bf[2][2];

#pragma unroll 1
  for (int p = 0; p < P; ++p) {
    const int b = p & 1;
    // ---- phase A: quadrant (0,0); stage q+1's A-X + B-Y
    LDA(b, 0); LDB(b, 0);
    if (p + 1 < P) { STG_A_(0, p + 1); STG_A_(2, p + 1);
                     STG_BY_(0, p + 1); STG_BY_(1, p + 1); }
    BAR; LGKM0; SCHED0;
    COMP(0, 0);
    BAR;
    // ---- phase B: quadrant (1,0) (bf0 held)
    LDA(b, 1);
    BAR; LGKM0; SCHED0;
    COMP(1, 0);
    BAR;
    // ---- phase C: quadrant (1,1) (af1 held); stage q+2's B-X (dead since A)
    LDB(b, 1);
    if (p + 2 < P) { STG_BX_(0, p + 2); STG_BX_(1, p + 2); }
    BAR; LGKM0; SCHED0;
    COMP(1, 1);
    BAR;
    // ---- phase D: quadrant (0,1) (bf1 held, af0 reloaded);
    //      stage q+2's A-Y (dead since B); counted wait for q+1's buffer
    LDA(b, 0);
    if (p + 2 < P) { STG_A_(1, p + 2); STG_A_(3, p + 2); }
    BAR; LGKM0; SCHED0;
    COMP(0, 1);
    if (p + 2 < P) { VMW4; } else { VMW0; }
    BAR;

    // ---- tile boundary: online-softmax epilogue (LDS/shuffle only)
    if (((p + 1) & 31) == 0) {
      const int tl = p >> 5;
      const int vcol0 = (tile_start + tl) * BN;
      float bv[4];
#pragma unroll
      for (int nf = 0; nf < 4; ++nf) {
        const unsigned int ub = bias_lds[tl * 256 + wn * 64 + nf * 16 + c0];
        bv[nf] = __uint_as_float(ub << 16);
      }
#pragma unroll
      for (int mf = 0; mf < 8; ++mf) {
#pragma unroll
        for (int reg = 0; reg < 4; ++reg) {
          const int rl  = wm * 128 + mf * 16 + g * 4 + reg;
          const int tgt = targ_s[rl];
          float vals[4];
          float vmax = -1e30f, tv = -1e30f;
#pragma unroll
          for (int nf = 0; nf < 4; ++nf) {
            const int col = vcol0 + wn * 64 + nf * 16 + c0;
            float v = acc[mf][nf][reg] + bv[nf];
            v = (col < VOCAB) ? v : -1e30f;
            vals[nf] = v;
            vmax = fmaxf(vmax, v);
            if (col == tgt) tv = v;
          }
          vmax = fmaxf(vmax, __shfl_xor(vmax, 1));
          vmax = fmaxf(vmax, __shfl_xor(vmax, 2));
          vmax = fmaxf(vmax, __shfl_xor(vmax, 4));
          vmax = fmaxf(vmax, __shfl_xor(vmax, 8));
          float ss = 0.f;
#pragma unroll
          for (int nf = 0; nf < 4; ++nf) ss += exp2f((vals[nf] - vmax) * L2E);
          ss += __shfl_xor(ss, 1);
          ss += __shfl_xor(ss, 2);
          ss += __shfl_xor(ss, 4);
          ss += __shfl_xor(ss, 8);
          tv = fmaxf(tv, __shfl_xor(tv, 1));
          tv = fmaxf(tv, __shfl_xor(tv, 2));
          tv = fmaxf(tv, __shfl_xor(tv, 4));
          tv = fmaxf(tv, __shfl_xor(tv, 8));
          if (c0 == 0) {
            m_w[wn * 256 + rl] = vmax;
            s_w[wn * 256 + rl] = ss;
            t_w[wn * 256 + rl] = tv;
          }
        }
      }
      LGKM0;
      BAR;
      if (tid < BM) {
        float mt = m_w[tid], st = s_w[tid], tvt = t_w[tid];
#pragma unroll
        for (int j = 1; j < 4; ++j) {
          const float mj = m_w[j * 256 + tid], sj = s_w[j * 256 + tid];
          const float nm = fmaxf(mt, mj);
          st = st * exp2f((mt - nm) * L2E) + sj * exp2f((mj - nm) * L2E);
          mt = nm;
          tvt = fmaxf(tvt, t_w[j * 256 + tid]);
        }
        const float M = M_run[tid], S = S_run[tid];
        const float nm = fmaxf(M, mt);
        S_run[tid] = S * exp2f((M - nm) * L2E) + st * exp2f((mt - nm) * L2E);
        M_run[tid] = nm;
        T_run[tid] = fmaxf(T_run[tid], tvt);
      }
      LGKM0;
      BAR;
      // reset accumulators for the next vocab tile
#pragma unroll
      for (int mf = 0; mf < 8; ++mf)
#pragma unroll
        for (int nf = 0; nf < 4; ++nf)
          acc[mf][nf] = (f32x4){0.f, 0.f, 0.f, 0.f};
    }
  }

  if (tid < BM) {
    pm[(size_t)chunk * NROWS + row0 + tid] = M_run[tid];
    ps[(size_t)chunk * NROWS + row0 + tid] = S_run[tid];
    const float tv = T_run[tid];
    if (tv > -1e29f) tlogit[row0 + tid] = tv;  // exactly one chunk per row
  }
}

// ---------------- merge partials -> per-row NLL ----------------
__global__ void merge_rows_kernel(const float* __restrict__ pm,
                                  const float* __restrict__ ps,
                                  const float* __restrict__ tlogit,
                                  const int* __restrict__ targ,
                                  float* __restrict__ nll) {
  const int r = blockIdx.x * blockDim.x + threadIdx.x;
  if (r >= NROWS) return;
  float M = -1e30f;
#pragma unroll
  for (int j = 0; j < NCHUNKS; ++j) M = fmaxf(M, pm[j * NROWS + r]);
  float S = 0.f;
#pragma unroll
  for (int j = 0; j < NCHUNKS; ++j)
    S += ps[j * NROWS + r] * exp2f((pm[j * NROWS + r] - M) * L2E);
  const int t = targ[r];
  nll[r] = (t == -100) ? 0.f : (M + logf(S) - tlogit[r]);
}

// ---------------- final mean ----------------
__global__ void final_reduce_kernel(const float* __restrict__ nll,
                                    const int* __restrict__ targ,
                                    float* __restrict__ out) {
  __shared__ float ssum[256];
  __shared__ float scnt[256];
  const int tid = threadIdx.x;
  float s = 0.f, c = 0.f;
  for (int r = tid; r < NROWS; r += 256) {
    s += nll[r];
    c += (targ[r] != -100) ? 1.f : 0.f;
  }
  ssum[tid] = s; scnt[tid] = c;
  __syncthreads();
  for (int off = 128; off > 0; off >>= 1) {
    if (tid < off) { ssum[tid] += ssum[tid + off]; scnt[tid] += scnt[tid + off]; }
    __syncthreads();
  }
  if (tid == 0) out[0] = ssum[0] / fmaxf(scnt[0], 1.f);
}

extern "C" void kernel_launch(void* const* d_in, const int* in_sizes, int n_in,
                              void* d_out, int out_size, void* d_ws, size_t ws_size,
                              hipStream_t stream) {
  const float* x    = (const float*)d_in[0];
  const float* W    = (const float*)d_in[1];
  const float* bias = (const float*)d_in[2];
  const int*   targ = (const int*)d_in[3];
  float* out = (float*)d_out;

  char* ws = (char*)d_ws;
  const size_t wb_bytes = (size_t)VOCAB_PAD * KDIM * 2;
  const size_t xb_bytes = (size_t)NROWS * KDIM * 2;
  const size_t pm_bytes = (size_t)NCHUNKS * NROWS * 4;
  const size_t tl_bytes = (size_t)NROWS * 4;

  size_t off = 0;
  unsigned short* wb = (unsigned short*)(ws + off); off += wb_bytes;
  unsigned short* xb = (unsigned short*)(ws + off); off += xb_bytes;
  float* pm   = (float*)(ws + off); off += pm_bytes;
  float* psum = (float*)(ws + off); off += pm_bytes;
  float* tlog = (float*)(ws + off); off += tl_bytes;
  float* nll  = (float*)(ws + off); off += tl_bytes;

  if (ws_size < off) {
    fprintf(stderr, "kernel_launch: ws too small (%zu < %zu)\n", ws_size, off);
    return;
  }

  (void)hipFuncSetAttribute((const void*)gemm_ce_kernel,
                            hipFuncAttributeMaxDynamicSharedMemorySize,
                            SMEM_BYTES);

  convert_w_kernel<<<4096, 256, 0, stream>>>((const float4*)W, (ushort4*)wb);
  convert_x_kernel<<<2048, 256, 0, stream>>>((const float4*)x, (ushort4*)xb);
  gemm_ce_kernel<<<ROWBLKS * NCHUNKS, 512, SMEM_BYTES, stream>>>(
      xb, wb, bias, targ, pm, psum, tlog);
  merge_rows_kernel<<<(NROWS + 255) / 256, 256, 0, stream>>>(pm, psum, tlog,
                                                             targ, nll);
  final_reduce_kernel<<<1, 256, 0, stream>>>(nll, targ, out);
}